// Round 9
// baseline (91.431 us; speedup 1.0000x reference)
//
#include <hip/hip_runtime.h>

// NMS-r BP decoder — one batch per WAVE (64-thread blocks, 64 blocks).
// Round-7 lesson: VALU trims did nothing; the cost is cross-wave coupling
// (8 waves x 6 phases of s_barrier + shared-LDS atomic interference).
// This round: each wave owns its whole batch -> ZERO inter-wave sync.
//  - lane owns 8 checks (m = 8*lane + j) and 16 marg cols (n = 2*lane + 128*j)
//  - single S[1024] LDS buffer per block: wave-lockstep program order
//    sequences all reads before the rebase writes before the atomic adds
//    (the in-loop __syncthreads is a 1-wave no-op that pins LDS ordering)
//  - 8 independent sort/LOO chains per lane = 8x ILP on the latency chain
//  - __launch_bounds__(64,1): 1 wave/SIMD, full VGPR budget, no spill
//  - float2-coalesced global I/O; ds_*_b64 LDS I/O (2-way alias free)
// Kept from round 7 (semantics-identical): sorted-permuted (v,cols,cv),
// 15-CE insertion network on |v|, sign-bit xor trick, S pre-based to
// sp1*soft so T is materialized by the atomics for free.

constexpr int BB    = 64;
constexpr int NCOL  = 1024;
constexpr int KDC   = 6;
constexpr int ITERS = 5;
constexpr int TOT   = BB * NCOL;
constexpr int CPL   = 8;     // checks per lane (512 / 64)
constexpr int JV    = 8;     // float2 column-groups per lane (1024 / 128)

__device__ __forceinline__ float softplusf(float x) {
    return fmaxf(x, 0.f) + log1pf(expf(-fabsf(x)));
}

__global__ void __launch_bounds__(64, 1) k_decode(
        const float* __restrict__ soft,      // [B,N]
        const int*   __restrict__ row_cols,  // [M,DC]
        const float* __restrict__ W1,        // [DC-1,4]
        const float* __restrict__ W2,        // [4]
        const float* __restrict__ bw1,
        const float* __restrict__ bw2,
        float* __restrict__ out) {           // [ITERS+1,B,N]
    __shared__ float S[NCOL];    // this wave's colsum buffer, base = sp1*soft

    const int l = threadIdx.x;   // lane 0..63
    const int b = blockIdx.x;

    const float sp1 = softplusf(bw1[0]);
    const float sp2 = softplusf(bw2[0]);
    const float dsp = sp2 - sp1;

    // collapsed NN: w = W1 @ W2 (5-vector)
    float w[KDC - 1];
#pragma unroll
    for (int j = 0; j < KDC - 1; ++j) {
        float a = 0.f;
#pragma unroll
        for (int q = 0; q < 4; ++q) a += W1[j * 4 + q] * W2[q];
        w[j] = a;
    }

    // load my 16 soft values (8x float2, coalesced), emit out[0], base S
    float2 sv[JV];
    const float* sbp = soft + b * NCOL;
    float* ob0 = out + b * NCOL;
#pragma unroll
    for (int j = 0; j < JV; ++j) {
        const int n = 2 * l + 128 * j;
        sv[j] = *reinterpret_cast<const float2*>(sbp + n);
        *reinterpret_cast<float2*>(ob0 + n) = sv[j];
        *reinterpret_cast<float2*>(&S[n]) =
            make_float2(sp1 * sv[j].x, sp1 * sv[j].y);
    }

    // my 8 checks' columns: row_cols[48*l .. 48*l+47], 12x int4
    int   cols[CPL * KDC];
    float cv[CPL * KDC];
    {
        const int4* rp = reinterpret_cast<const int4*>(row_cols) + 12 * l;
#pragma unroll
        for (int t = 0; t < 12; ++t) {
            const int4 q = rp[t];
            cols[4 * t]     = q.x;  cols[4 * t + 1] = q.y;
            cols[4 * t + 2] = q.z;  cols[4 * t + 3] = q.w;
        }
#pragma unroll
        for (int e = 0; e < CPL * KDC; ++e) cv[e] = 0.f;
    }
    __syncthreads();   // 1 wave: just pins LDS init before phase 0

#pragma unroll 1       // keep icache small; phase body ~700 instrs
    for (int p = 0; p < ITERS; ++p) {
        // ---- all 48 T-gathers first (batched: latency overlaps) ----
        float v[CPL * KDC];
#pragma unroll
        for (int e = 0; e < CPL * KDC; ++e) v[e] = S[cols[e]] - cv[e];

        // ---- marg reads for iter p (must precede rebase; lockstep order) ----
        float2 mg[JV];
#pragma unroll
        for (int j = 0; j < JV; ++j) {
            const int n = 2 * l + 128 * j;
            mg[j] = *reinterpret_cast<const float2*>(&S[n]);
        }
        if (p >= 1) {
            float* op = out + (size_t)p * TOT + b * NCOL;
#pragma unroll
            for (int j = 0; j < JV; ++j) {
                const int n = 2 * l + 128 * j;
                *reinterpret_cast<float2*>(op + n) = make_float2(
                    fmaf(dsp, sv[j].x, mg[j].x), fmaf(dsp, sv[j].y, mg[j].y));
            }
        }
        // ---- rebase S for next colsum (after ALL reads this phase) ----
#pragma unroll
        for (int j = 0; j < JV; ++j) {
            const int n = 2 * l + 128 * j;
            *reinterpret_cast<float2*>(&S[n]) =
                make_float2(sp1 * sv[j].x, sp1 * sv[j].y);
        }

        // ---- 8 independent check updates ----
#pragma unroll
        for (int jc = 0; jc < CPL; ++jc) {
            const int e0 = jc * KDC;
#define CE(i, j) { bool sw = fabsf(v[e0+(i)]) > fabsf(v[e0+(j)]);             \
            float tv = sw ? v[e0+(j)] : v[e0+(i)];                            \
            v[e0+(j)] = sw ? v[e0+(i)] : v[e0+(j)]; v[e0+(i)] = tv;           \
            int tc = sw ? cols[e0+(j)] : cols[e0+(i)];                        \
            cols[e0+(j)] = sw ? cols[e0+(i)] : cols[e0+(j)]; cols[e0+(i)] = tc; }
            CE(0,1)
            CE(1,2) CE(0,1)
            CE(2,3) CE(1,2) CE(0,1)
            CE(3,4) CE(2,3) CE(1,2) CE(0,1)
            CE(4,5) CE(3,4) CE(2,3) CE(1,2) CE(0,1)
#undef CE
            float        mgv[KDC];
            unsigned int sb[KDC];
#pragma unroll
            for (int r = 0; r < KDC; ++r) {
                mgv[r] = fabsf(v[e0 + r]);
                sb[r]  = __float_as_uint(v[e0 + r]) & 0x80000000u;
            }
            const unsigned int Pb = sb[0] ^ sb[1] ^ sb[2] ^ sb[3] ^ sb[4] ^ sb[5];

            float pre[KDC];
            pre[0] = 0.f;
#pragma unroll
            for (int r = 0; r < KDC - 1; ++r) pre[r + 1] = pre[r] + mgv[r] * w[r];
            float suf[KDC];
            suf[KDC - 1] = 0.f;
#pragma unroll
            for (int r = KDC - 2; r >= 0; --r) suf[r] = suf[r + 1] + mgv[r + 1] * w[r];

#pragma unroll
            for (int r = 0; r < KDC; ++r) {
                const float cvn = __uint_as_float(
                    __float_as_uint(pre[r] + suf[r]) | (Pb ^ sb[r]));
                cv[e0 + r] = cvn;                       // aligned with cols
                atomicAdd(&S[cols[e0 + r]], cvn);       // ds_add_f32, wave-local
            }
        }
        __syncthreads();   // 1-wave no-op barrier: pins adds before next reads
    }

    // final marginalize: S now holds T_ITERS
    float* op = out + (size_t)ITERS * TOT + b * NCOL;
#pragma unroll
    for (int j = 0; j < JV; ++j) {
        const int n = 2 * l + 128 * j;
        const float2 t = *reinterpret_cast<const float2*>(&S[n]);
        *reinterpret_cast<float2*>(op + n) = make_float2(
            fmaf(dsp, sv[j].x, t.x), fmaf(dsp, sv[j].y, t.y));
    }
}

extern "C" void kernel_launch(void* const* d_in, const int* in_sizes, int n_in,
                              void* d_out, int out_size, void* d_ws, size_t ws_size,
                              hipStream_t stream) {
    const float* soft     = (const float*)d_in[0];
    // d_in[1] labels (int64) unused; d_in[2] dense H unused
    const int*   row_cols = (const int*)d_in[3];
    const float* W1       = (const float*)d_in[4];
    const float* W2       = (const float*)d_in[5];
    const float* bw1      = (const float*)d_in[6];
    const float* bw2      = (const float*)d_in[7];
    float* out = (float*)d_out;

    k_decode<<<dim3(BB), dim3(64), 0, stream>>>(soft, row_cols, W1, W2,
                                                bw1, bw2, out);
}